// Round 3
// baseline (152.493 us; speedup 1.0000x reference)
//
#include <hip/hip_runtime.h>
#include <stdint.h>
#include <math.h>

// Problem constants (from reference: B=2048, D=512, TAU=0.5)
#define DIM       512
#define NROWS     8192      // 4*B
#define HALF_ROWS 4096      // 2*B
#define NT        32        // 8192 / 256 tiles per side
#define NTRI      528       // NT*(NT+1)/2 upper-triangle tiles
#define NXCD      8
#define TPX       66        // tiles per XCD (528/8, exact)
#define GRID_G    512       // gram grid: 16 blocks (dispatched first) take 2 tiles

typedef float  floatx16 __attribute__((ext_vector_type(16)));
typedef __bf16 bf16x8   __attribute__((ext_vector_type(8)));

__device__ __forceinline__ void async_copy16(const unsigned short* g, unsigned short* l) {
    __builtin_amdgcn_global_load_lds(
        (const __attribute__((address_space(1))) uint32_t*)(g),
        (__attribute__((address_space(3))) uint32_t*)(l),
        16, 0, 0);
}

// L2-normalize rows of [emb_i; emb_j] -> bf16 rep[8192][512]; also zero ws.
__global__ __launch_bounds__(256) void normalize_kernel(
    const float* __restrict__ emb_i, const float* __restrict__ emb_j,
    unsigned short* __restrict__ rep, double* __restrict__ ws)
{
    if (blockIdx.x == 0 && threadIdx.x == 0) {
        ws[0] = 0.0; ws[1] = 0.0;
        ((unsigned long long*)ws)[2] = 0ull;   // completion counter
    }
    const int wave = threadIdx.x >> 6;
    const int lane = threadIdx.x & 63;
    const int row  = blockIdx.x * 4 + wave;
    const float* src = (row < HALF_ROWS) ? (emb_i + (size_t)row * DIM)
                                         : (emb_j + (size_t)(row - HALF_ROWS) * DIM);
    const int c = lane * 8;
    float4 v0 = *(const float4*)(src + c);
    float4 v1 = *(const float4*)(src + c + 4);
    float s = v0.x*v0.x + v0.y*v0.y + v0.z*v0.z + v0.w*v0.w
            + v1.x*v1.x + v1.y*v1.y + v1.z*v1.z + v1.w*v1.w;
    #pragma unroll
    for (int off = 32; off; off >>= 1) s += __shfl_xor(s, off, 64);
    const float inv = 1.0f / fmaxf(sqrtf(s), 1e-12f);
    float f[8] = {v0.x*inv, v0.y*inv, v0.z*inv, v0.w*inv,
                  v1.x*inv, v1.y*inv, v1.z*inv, v1.w*inv};
    union { unsigned short h[8]; uint4 u; } pk;
    #pragma unroll
    for (int t = 0; t < 8; ++t) {   // fp32 -> bf16 RNE
        uint32_t b = __float_as_uint(f[t]);
        b += 0x7FFFu + ((b >> 16) & 1u);
        pk.h[t] = (unsigned short)(b >> 16);
    }
    *(uint4*)(rep + (size_t)row * DIM + c) = pk.u;
}

// Stage one 128x64 bf16 half-tile (16 KB) into LDS (linear dest; bank swizzle
// byte^=(row&7)<<4 applied by permuting the GLOBAL source slot — rule #21).
__device__ __forceinline__ void stage_half(const unsigned short* __restrict__ rep,
    int rowbase, int k0, unsigned short* lds, int tid)
{
    #pragma unroll
    for (int l = 0; l < 2; ++l) {
        const int ch  = l * 512 + tid;          // 1024 chunks of 16 B
        const int row = ch >> 3;                // 8 chunks per 64-col row
        const int s   = ch & 7;
        const int col = (s ^ (row & 7)) << 3;   // pre-swizzled source slot
        async_copy16(rep + (size_t)(rowbase + row) * DIM + (k0 + col), lds + ch * 8);
    }
}

#define PH_BAR1() do { __builtin_amdgcn_s_barrier(); \
    asm volatile("s_waitcnt lgkmcnt(0)" ::: "memory"); \
    __builtin_amdgcn_sched_barrier(0); } while (0)

#define PH_BAR2() do { __builtin_amdgcn_s_barrier(); \
    __builtin_amdgcn_sched_barrier(0); } while (0)

#define WAIT_VM(N) asm volatile("s_waitcnt vmcnt(" #N ")" ::: "memory")

// A-fragments for one 64-row half (MH in {0,1}): 2 m-tiles x 4 k-frags.
// 32x32x16 operand layout: lane holds A[row=lane&31][k=(lane>>5)*8 + e].
#define LOAD_A(BUF, MH) do { const unsigned short* Ah_ = sA[BUF][wm]; \
    _Pragma("unroll") for (int mt = 0; mt < 2; ++mt) { \
        const char* rp_ = (const char*)Ah_ + ((MH)*64 + mt*32 + r32) * 128; \
        _Pragma("unroll") for (int kf = 0; kf < 4; ++kf) \
            a[mt][kf] = *(const bf16x8*)(rp_ + ((kf*32 + half16) ^ swz)); } } while (0)

// B-fragments for one 32-col tile (NJ in {0,1}): 4 k-frags.
#define LOAD_B(BUF, NJ, DST) do { const unsigned short* Bh_ = sB[BUF][wn >> 1]; \
    const char* rp_ = (const char*)Bh_ + (((wn & 1)*64 + (NJ)*32 + r32) * 128); \
    _Pragma("unroll") for (int kf = 0; kf < 4; ++kf) \
        DST[kf] = *(const bf16x8*)(rp_ + ((kf*32 + half16) ^ swz)); } while (0)

// One phase's MFMA cluster: 2 m-tiles x 1 n-tile x 4 k = 8 x mfma_32x32x16.
#define MFMA_Q(MH, NJ, BB) do { \
    __builtin_amdgcn_s_setprio(1); \
    _Pragma("unroll") for (int mt = 0; mt < 2; ++mt) \
      _Pragma("unroll") for (int kf = 0; kf < 4; ++kf) \
        acc[(MH)*2 + mt][NJ] = __builtin_amdgcn_mfma_f32_32x32x16_bf16( \
            a[mt][kf], BB[kf], acc[(MH)*2 + mt][NJ], 0, 0, 0); \
    __builtin_amdgcn_s_setprio(0); } while (0)

// 8-phase double-buffered 256x256 Gram tile + fused exp/band reduction.
// 8 waves (2M x 4N), per-wave 128x64 output; BK=64; counted vmcnt(4).
__global__ __launch_bounds__(512, 2) void gram_kernel(
    const unsigned short* __restrict__ rep, double* __restrict__ ws,
    float* __restrict__ out)
{
    __shared__ unsigned short sA[2][2][128 * 64];  // [buf][half] 64 KB
    __shared__ unsigned short sB[2][2][128 * 64];  // 64 KB
    __shared__ float red[16];

    const int tid  = threadIdx.x;
    const int wave = tid >> 6, lane = tid & 63;
    const int wm = wave >> 2, wn = wave & 3;       // 2 x 4 waves
    const int r32 = lane & 31, half16 = (lane >> 5) * 16;
    const int swz = (r32 & 7) << 4;                // bank swizzle (matches staging)

    // XCD-chunked tile mapping: dispatch round-robins blockIdx%8 across XCDs;
    // give XCD x tiles [x*66, x*66+66). Slots 0,1 (blockIdx<16, dispatched
    // FIRST) each take 2 tiles -> 512 blocks cover 528 tiles, makespan 2T.
    const int x = blockIdx.x & 7, slot = blockIdx.x >> 3;
    int u_first, ntile;
    if (slot < 2) { u_first = x * TPX + slot * 2; ntile = 2; }
    else          { u_first = x * TPX + slot + 2; ntile = 1; }

    for (int t = 0; t < ntile; ++t) {
        const int u = u_first + t;
        // Triangular decode u -> (bi, bj), bj >= bi.
        int bi = (int)((2.0f * NT + 1.0f
                 - sqrtf((2.0f * NT + 1.0f) * (2.0f * NT + 1.0f) - 8.0f * (float)u)) * 0.5f);
        while ((bi + 1) * NT - ((bi + 1) * bi) / 2 <= u) ++bi;
        while (bi * NT - (bi * (bi - 1)) / 2 > u) --bi;
        const int bj = bi + (u - (bi * NT - (bi * (bi - 1)) / 2));
        const int i0 = bi * 256, j0 = bj * 256;

        floatx16 acc[4][2];
        #pragma unroll
        for (int p = 0; p < 4; ++p)
            #pragma unroll
            for (int q = 0; q < 2; ++q)
                #pragma unroll
                for (int e = 0; e < 16; ++e) acc[p][q][e] = 0.0f;

        bf16x8 a[2][4], bL[4], bR[4];

        // ---- Prologue: K-tile0 complete + K-tile1 B-halves ----
        stage_half(rep, i0,       0,  sA[0][0], tid);
        stage_half(rep, i0 + 128, 0,  sA[0][1], tid);
        stage_half(rep, j0,       0,  sB[0][0], tid);
        stage_half(rep, j0 + 128, 0,  sB[0][1], tid);
        stage_half(rep, j0,       64, sB[1][0], tid);
        stage_half(rep, j0 + 128, 64, sB[1][1], tid);
        WAIT_VM(4);                   // tile0 landed; tile1 B's in flight
        __builtin_amdgcn_s_barrier();
        __builtin_amdgcn_sched_barrier(0);

        // ---- Main loop: compute K-tiles (T, T+1); stage (T+1 A, T+2 B/A, T+3 B)
        int kA1 = 64, kT2 = 128, kT3 = 192;
        for (int it = 0; it < 3; ++it) {
            LOAD_A(0, 0); LOAD_B(0, 0, bL);
            stage_half(rep, i0, kA1, sA[1][0], tid);
            PH_BAR1(); MFMA_Q(0, 0, bL); PH_BAR2();
            LOAD_B(0, 1, bR);
            stage_half(rep, i0 + 128, kA1, sA[1][1], tid);
            PH_BAR1(); MFMA_Q(0, 1, bR); PH_BAR2();
            LOAD_A(0, 1);
            stage_half(rep, j0, kT2, sB[0][0], tid);
            PH_BAR1(); MFMA_Q(1, 1, bR); PH_BAR2();
            stage_half(rep, j0 + 128, kT2, sB[0][1], tid);
            WAIT_VM(4);
            PH_BAR1(); MFMA_Q(1, 0, bL); PH_BAR2();
            LOAD_A(1, 0); LOAD_B(1, 0, bL);
            stage_half(rep, i0, kT2, sA[0][0], tid);
            PH_BAR1(); MFMA_Q(0, 0, bL); PH_BAR2();
            LOAD_B(1, 1, bR);
            stage_half(rep, i0 + 128, kT2, sA[0][1], tid);
            PH_BAR1(); MFMA_Q(0, 1, bR); PH_BAR2();
            LOAD_A(1, 1);
            stage_half(rep, j0, kT3, sB[1][0], tid);
            PH_BAR1(); MFMA_Q(1, 1, bR); PH_BAR2();
            stage_half(rep, j0 + 128, kT3, sB[1][1], tid);
            WAIT_VM(4);
            PH_BAR1(); MFMA_Q(1, 0, bL); PH_BAR2();
            kA1 += 128; kT2 += 128; kT3 += 128;
        }

        // ---- Epilogue: K-tiles 6 (buf0), 7 (buf1) ----
        LOAD_A(0, 0); LOAD_B(0, 0, bL);
        stage_half(rep, i0, 448, sA[1][0], tid);
        PH_BAR1(); MFMA_Q(0, 0, bL); PH_BAR2();
        LOAD_B(0, 1, bR);
        stage_half(rep, i0 + 128, 448, sA[1][1], tid);
        PH_BAR1(); MFMA_Q(0, 1, bR); PH_BAR2();
        LOAD_A(0, 1);
        PH_BAR1(); MFMA_Q(1, 1, bR); PH_BAR2();
        WAIT_VM(0);                   // drain: K-tile 7 fully landed
        PH_BAR1(); MFMA_Q(1, 0, bL); PH_BAR2();
        LOAD_A(1, 0); LOAD_B(1, 0, bL);
        PH_BAR1(); MFMA_Q(0, 0, bL); PH_BAR2();
        LOAD_B(1, 1, bR);
        PH_BAR1(); MFMA_Q(0, 1, bR); PH_BAR2();
        LOAD_A(1, 1);
        PH_BAR1(); MFMA_Q(1, 1, bR); PH_BAR2();
        MFMA_Q(1, 0, bL);             // registers only, no barrier

        // ---- exp(sim/tau) = exp2(sim * 2/ln2); band + total sums ----
        // 32x32 C/D layout: col = lane&31, row = (reg&3) + 8*(reg>>2) + 4*(lane>>5)
        float s_all = 0.0f, s_pos = 0.0f;
        const float LOG2E2 = 2.885390081777927f;  // 2 / ln(2)
        const int rbase = (half16 >> 2);          // 4*(lane>>5)
        #pragma unroll
        for (int mi = 0; mi < 4; ++mi) {
            const int ib = i0 + wm * 128 + mi * 32 + rbase;
            #pragma unroll
            for (int nj = 0; nj < 2; ++nj) {
                const int j = j0 + wn * 64 + nj * 32 + r32;
                const floatx16 v = acc[mi][nj];
                #pragma unroll
                for (int reg = 0; reg < 16; ++reg) {
                    const int i = ib + (reg & 3) + 8 * (reg >> 2);
                    const float ex = exp2f(v[reg] * LOG2E2);
                    if (i != j) s_all += ex;
                    const int d = j - i;          // upper triangle: positive bands
                    if (d == 2048 || d == 4096 || d == 6144) s_pos += ex;
                }
            }
        }
        #pragma unroll
        for (int off = 32; off; off >>= 1) {
            s_all += __shfl_xor(s_all, off, 64);
            s_pos += __shfl_xor(s_pos, off, 64);
        }
        if (lane == 0) { red[wave] = s_all; red[8 + wave] = s_pos; }
        __syncthreads();
        if (tid == 0) {
            float ta = 0.0f, tp = 0.0f;
            #pragma unroll
            for (int w2 = 0; w2 < 8; ++w2) { ta += red[w2]; tp += red[8 + w2]; }
            const float wgt = (bi == bj) ? 1.0f : 2.0f;
            atomicAdd(&ws[0], (double)(ta * wgt));
            atomicAdd(&ws[1], (double)(tp * wgt));
            __threadfence();
            unsigned* ctr = (unsigned*)(ws + 2);
            const unsigned done = atomicAdd(ctr, 1u);
            if (done == NTRI - 1) {               // last tile: fused finalize
                __threadfence();
                const double nom = atomicAdd(&ws[1], 0.0);
                const double den = atomicAdd(&ws[0], 0.0) - nom;
                out[0] = (float)(-log(nom / den) / (double)NROWS);
            }
        }
        __syncthreads();   // protect red[] before next tile reuses it
    }
}

extern "C" void kernel_launch(void* const* d_in, const int* in_sizes, int n_in,
                              void* d_out, int out_size, void* d_ws, size_t ws_size,
                              hipStream_t stream) {
    const float* emb_i = (const float*)d_in[0];
    const float* emb_j = (const float*)d_in[1];
    float* out = (float*)d_out;
    double* ws = (double*)d_ws;                                   // accums + counter
    unsigned short* rep = (unsigned short*)((char*)d_ws + 256);   // bf16 [8192][512]

    hipLaunchKernelGGL(normalize_kernel, dim3(NROWS / 4), dim3(256), 0, stream,
                       emb_i, emb_j, rep, ws);
    hipLaunchKernelGGL(gram_kernel, dim3(GRID_G), dim3(512), 0, stream, rep, ws, out);
}

// Round 4
// 150.267 us; speedup vs baseline: 1.0148x; 1.0148x over previous
//
#include <hip/hip_runtime.h>
#include <stdint.h>
#include <math.h>

// Problem constants (from reference: B=2048, D=512, TAU=0.5)
#define DIM       512
#define NROWS     8192      // 4*B
#define HALF_ROWS 4096      // 2*B
#define NT        32        // 8192 / 256 tiles per side
#define NTRI      528       // NT*(NT+1)/2 upper-triangle tiles
#define GRID_G    528       // one block per tile; blk%8 -> XCD, blk/8 -> slot 0..65

typedef float  floatx16 __attribute__((ext_vector_type(16)));
typedef __bf16 bf16x8   __attribute__((ext_vector_type(8)));

__device__ __forceinline__ void async_copy16(const unsigned short* g, unsigned short* l) {
    __builtin_amdgcn_global_load_lds(
        (const __attribute__((address_space(1))) uint32_t*)(g),
        (__attribute__((address_space(3))) uint32_t*)(l),
        16, 0, 0);
}

// L2-normalize rows of [emb_i; emb_j] -> bf16 rep[8192][512]; also zero ws.
__global__ __launch_bounds__(256) void normalize_kernel(
    const float* __restrict__ emb_i, const float* __restrict__ emb_j,
    unsigned short* __restrict__ rep, double* __restrict__ ws)
{
    if (blockIdx.x == 0 && threadIdx.x == 0) {
        ws[0] = 0.0; ws[1] = 0.0;
        ((unsigned long long*)ws)[2] = 0ull;   // completion counter
    }
    const int wave = threadIdx.x >> 6;
    const int lane = threadIdx.x & 63;
    const int row  = blockIdx.x * 4 + wave;
    const float* src = (row < HALF_ROWS) ? (emb_i + (size_t)row * DIM)
                                         : (emb_j + (size_t)(row - HALF_ROWS) * DIM);
    const int c = lane * 8;
    float4 v0 = *(const float4*)(src + c);
    float4 v1 = *(const float4*)(src + c + 4);
    float s = v0.x*v0.x + v0.y*v0.y + v0.z*v0.z + v0.w*v0.w
            + v1.x*v1.x + v1.y*v1.y + v1.z*v1.z + v1.w*v1.w;
    #pragma unroll
    for (int off = 32; off; off >>= 1) s += __shfl_xor(s, off, 64);
    const float inv = 1.0f / fmaxf(sqrtf(s), 1e-12f);
    float f[8] = {v0.x*inv, v0.y*inv, v0.z*inv, v0.w*inv,
                  v1.x*inv, v1.y*inv, v1.z*inv, v1.w*inv};
    union { unsigned short h[8]; uint4 u; } pk;
    #pragma unroll
    for (int t = 0; t < 8; ++t) {   // fp32 -> bf16 RNE
        uint32_t b = __float_as_uint(f[t]);
        b += 0x7FFFu + ((b >> 16) & 1u);
        pk.h[t] = (unsigned short)(b >> 16);
    }
    *(uint4*)(rep + (size_t)row * DIM + c) = pk.u;
}

// Stage one 128x64 bf16 half-tile (16 KB) into LDS (linear dest; bank swizzle
// byte^=(row&7)<<4 applied by permuting the GLOBAL source slot — rule #21).
__device__ __forceinline__ void stage_half(const unsigned short* __restrict__ rep,
    int rowbase, int k0, unsigned short* lds, int tid)
{
    #pragma unroll
    for (int l = 0; l < 2; ++l) {
        const int ch  = l * 512 + tid;          // 1024 chunks of 16 B
        const int row = ch >> 3;                // 8 chunks per 64-col row
        const int s   = ch & 7;
        const int col = (s ^ (row & 7)) << 3;   // pre-swizzled source slot
        async_copy16(rep + (size_t)(rowbase + row) * DIM + (k0 + col), lds + ch * 8);
    }
}

#define PH_BAR1() do { __builtin_amdgcn_s_barrier(); \
    asm volatile("s_waitcnt lgkmcnt(0)" ::: "memory"); \
    __builtin_amdgcn_sched_barrier(0); } while (0)

#define PH_BAR2() do { __builtin_amdgcn_s_barrier(); \
    __builtin_amdgcn_sched_barrier(0); } while (0)

#define WAIT_VM(N) asm volatile("s_waitcnt vmcnt(" #N ")" ::: "memory")

// A-fragments for one 64-row half (MH in {0,1}): 2 m-tiles x 4 k-frags.
// 32x32x16 operand layout: lane holds A[row=lane&31][k=(lane>>5)*8 + e].
#define LOAD_A(BUF, MH) do { const unsigned short* Ah_ = sA[BUF][wm]; \
    _Pragma("unroll") for (int mt = 0; mt < 2; ++mt) { \
        const char* rp_ = (const char*)Ah_ + ((MH)*64 + mt*32 + r32) * 128; \
        _Pragma("unroll") for (int kf = 0; kf < 4; ++kf) \
            a[mt][kf] = *(const bf16x8*)(rp_ + ((kf*32 + half16) ^ swz)); } } while (0)

// B-fragments for one 32-col tile (NJ in {0,1}): 4 k-frags.
#define LOAD_B(BUF, NJ, DST) do { const unsigned short* Bh_ = sB[BUF][wn >> 1]; \
    const char* rp_ = (const char*)Bh_ + (((wn & 1)*64 + (NJ)*32 + r32) * 128); \
    _Pragma("unroll") for (int kf = 0; kf < 4; ++kf) \
        DST[kf] = *(const bf16x8*)(rp_ + ((kf*32 + half16) ^ swz)); } while (0)

// One phase's MFMA cluster: 2 m-tiles x 1 n-tile x 4 k = 8 x mfma_32x32x16.
#define MFMA_Q(MH, NJ, BB) do { \
    __builtin_amdgcn_s_setprio(1); \
    _Pragma("unroll") for (int mt = 0; mt < 2; ++mt) \
      _Pragma("unroll") for (int kf = 0; kf < 4; ++kf) \
        acc[(MH)*2 + mt][NJ] = __builtin_amdgcn_mfma_f32_32x32x16_bf16( \
            a[mt][kf], BB[kf], acc[(MH)*2 + mt][NJ], 0, 0, 0); \
    __builtin_amdgcn_s_setprio(0); } while (0)

// 8-phase double-buffered 256x256 Gram tile + fused exp/band reduction.
// 8 waves (2M x 4N), per-wave 128x64 output; BK=64; counted vmcnt(4).
// NOTE: no min-waves clause — LDS (128.5 KB) already caps at 1 block/CU;
// capping VGPR at 256 caused 10 MB of scratch spill in R3.
__global__ __launch_bounds__(512) void gram_kernel(
    const unsigned short* __restrict__ rep, double* __restrict__ ws,
    float* __restrict__ out)
{
    __shared__ unsigned short sA[2][2][128 * 64];  // [buf][half] 64 KB
    __shared__ unsigned short sB[2][2][128 * 64];  // 64 KB
    __shared__ float red[16];

    const int tid  = threadIdx.x;
    const int wave = tid >> 6, lane = tid & 63;
    const int wm = wave >> 2, wn = wave & 3;       // 2 x 4 waves
    const int r32 = lane & 31, half16 = (lane >> 5) * 16;
    const int swz = (r32 & 7) << 4;                // bank swizzle (matches staging)

    // ---- Tournament tile schedule (L2 locality per XCD) ----
    // 32 panels (256 rows each) in 8 groups of 4. XCD x (= blk%8, HW round-robin):
    //   slot t<10 : diagonal group-block tiles (panels of G_x only)
    //   t>=10    : round r=(t-10)/8 of a round-robin tournament on the 8 groups;
    //              XCD x does its 8-tile half of match (x, partner(x,r)).
    // Concurrent working set per XCD ~= 8 panels = 2 MB < 4 MB L2.
    const int x = blockIdx.x & 7;
    const int t = blockIdx.x >> 3;                 // 0..65
    int bi, bj;
    if (t < 10) {
        const int a = (0xE9500 >> (2 * t)) & 3;    // packed (a,b), a<=b, of the
        const int b = (0xFBEE4 >> (2 * t)) & 3;    // 10 within-group tiles
        bi = x * 4 + a;  bj = x * 4 + b;
    } else {
        const int r = (t - 10) >> 3, k = (t - 10) & 7;
        int p;                                     // tournament partner (circle)
        if (x == 7) p = r;
        else if (x == r) p = 7;
        else { p = (2 * r - x + 7) % 7; }
        const int g = (x < p) ? x : p, h = (x < p) ? p : x;
        const int m16 = (x == g) ? k : 8 + k;      // split match's 16 tiles 8/8
        bi = g * 4 + (m16 >> 2);  bj = h * 4 + (m16 & 3);
    }
    const int i0 = bi * 256, j0 = bj * 256;

    floatx16 acc[4][2];
    #pragma unroll
    for (int p2 = 0; p2 < 4; ++p2)
        #pragma unroll
        for (int q = 0; q < 2; ++q)
            #pragma unroll
            for (int e = 0; e < 16; ++e) acc[p2][q][e] = 0.0f;

    bf16x8 a[2][4], bL[4], bR[4];

    // ---- Prologue: K-tile0 complete + K-tile1 B-halves ----
    stage_half(rep, i0,       0,  sA[0][0], tid);
    stage_half(rep, i0 + 128, 0,  sA[0][1], tid);
    stage_half(rep, j0,       0,  sB[0][0], tid);
    stage_half(rep, j0 + 128, 0,  sB[0][1], tid);
    stage_half(rep, j0,       64, sB[1][0], tid);
    stage_half(rep, j0 + 128, 64, sB[1][1], tid);
    WAIT_VM(4);                   // tile0 landed; tile1 B's in flight
    __builtin_amdgcn_s_barrier();
    __builtin_amdgcn_sched_barrier(0);

    // ---- Main loop: compute K-tiles (T, T+1); stage (T+1 A, T+2 B/A, T+3 B)
    int kA1 = 64, kT2 = 128, kT3 = 192;
    for (int it = 0; it < 3; ++it) {
        LOAD_A(0, 0); LOAD_B(0, 0, bL);
        stage_half(rep, i0, kA1, sA[1][0], tid);
        PH_BAR1(); MFMA_Q(0, 0, bL); PH_BAR2();
        LOAD_B(0, 1, bR);
        stage_half(rep, i0 + 128, kA1, sA[1][1], tid);
        PH_BAR1(); MFMA_Q(0, 1, bR); PH_BAR2();
        LOAD_A(0, 1);
        stage_half(rep, j0, kT2, sB[0][0], tid);
        PH_BAR1(); MFMA_Q(1, 1, bR); PH_BAR2();
        stage_half(rep, j0 + 128, kT2, sB[0][1], tid);
        WAIT_VM(4);
        PH_BAR1(); MFMA_Q(1, 0, bL); PH_BAR2();
        LOAD_A(1, 0); LOAD_B(1, 0, bL);
        stage_half(rep, i0, kT2, sA[0][0], tid);
        PH_BAR1(); MFMA_Q(0, 0, bL); PH_BAR2();
        LOAD_B(1, 1, bR);
        stage_half(rep, i0 + 128, kT2, sA[0][1], tid);
        PH_BAR1(); MFMA_Q(0, 1, bR); PH_BAR2();
        LOAD_A(1, 1);
        stage_half(rep, j0, kT3, sB[1][0], tid);
        PH_BAR1(); MFMA_Q(1, 1, bR); PH_BAR2();
        stage_half(rep, j0 + 128, kT3, sB[1][1], tid);
        WAIT_VM(4);
        PH_BAR1(); MFMA_Q(1, 0, bL); PH_BAR2();
        kA1 += 128; kT2 += 128; kT3 += 128;
    }

    // ---- Epilogue: K-tiles 6 (buf0), 7 (buf1) ----
    LOAD_A(0, 0); LOAD_B(0, 0, bL);
    stage_half(rep, i0, 448, sA[1][0], tid);
    PH_BAR1(); MFMA_Q(0, 0, bL); PH_BAR2();
    LOAD_B(0, 1, bR);
    stage_half(rep, i0 + 128, 448, sA[1][1], tid);
    PH_BAR1(); MFMA_Q(0, 1, bR); PH_BAR2();
    LOAD_A(0, 1);
    PH_BAR1(); MFMA_Q(1, 1, bR); PH_BAR2();
    WAIT_VM(0);                   // drain: K-tile 7 fully landed
    PH_BAR1(); MFMA_Q(1, 0, bL); PH_BAR2();
    LOAD_A(1, 0); LOAD_B(1, 0, bL);
    PH_BAR1(); MFMA_Q(0, 0, bL); PH_BAR2();
    LOAD_B(1, 1, bR);
    PH_BAR1(); MFMA_Q(0, 1, bR); PH_BAR2();
    LOAD_A(1, 1);
    PH_BAR1(); MFMA_Q(1, 1, bR); PH_BAR2();
    MFMA_Q(1, 0, bL);             // registers only, no barrier

    // ---- exp(sim/tau) = exp2(sim * 2/ln2); band + total sums ----
    // 32x32 C/D layout: col = lane&31, row = (reg&3) + 8*(reg>>2) + 4*(lane>>5)
    float s_all = 0.0f, s_pos = 0.0f;
    const float LOG2E2 = 2.885390081777927f;  // 2 / ln(2)
    const int rbase = (half16 >> 2);          // 4*(lane>>5)
    #pragma unroll
    for (int mi = 0; mi < 4; ++mi) {
        const int ib = i0 + wm * 128 + mi * 32 + rbase;
        #pragma unroll
        for (int nj = 0; nj < 2; ++nj) {
            const int j = j0 + wn * 64 + nj * 32 + r32;
            const floatx16 v = acc[mi][nj];
            #pragma unroll
            for (int reg = 0; reg < 16; ++reg) {
                const int i = ib + (reg & 3) + 8 * (reg >> 2);
                const float ex = exp2f(v[reg] * LOG2E2);
                if (i != j) s_all += ex;
                const int d = j - i;          // upper triangle: positive bands
                if (d == 2048 || d == 4096 || d == 6144) s_pos += ex;
            }
        }
    }
    #pragma unroll
    for (int off = 32; off; off >>= 1) {
        s_all += __shfl_xor(s_all, off, 64);
        s_pos += __shfl_xor(s_pos, off, 64);
    }
    if (lane == 0) { red[wave] = s_all; red[8 + wave] = s_pos; }
    __syncthreads();
    if (tid == 0) {
        float ta = 0.0f, tp = 0.0f;
        #pragma unroll
        for (int w2 = 0; w2 < 8; ++w2) { ta += red[w2]; tp += red[8 + w2]; }
        const float wgt = (bi == bj) ? 1.0f : 2.0f;
        atomicAdd(&ws[0], (double)(ta * wgt));
        atomicAdd(&ws[1], (double)(tp * wgt));
        __threadfence();
        unsigned* ctr = (unsigned*)(ws + 2);
        const unsigned done = atomicAdd(ctr, 1u);
        if (done == NTRI - 1) {               // last tile: fused finalize
            __threadfence();
            const double nom = atomicAdd(&ws[1], 0.0);
            const double den = atomicAdd(&ws[0], 0.0) - nom;
            out[0] = (float)(-log(nom / den) / (double)NROWS);
        }
    }
}

extern "C" void kernel_launch(void* const* d_in, const int* in_sizes, int n_in,
                              void* d_out, int out_size, void* d_ws, size_t ws_size,
                              hipStream_t stream) {
    const float* emb_i = (const float*)d_in[0];
    const float* emb_j = (const float*)d_in[1];
    float* out = (float*)d_out;
    double* ws = (double*)d_ws;                                   // accums + counter
    unsigned short* rep = (unsigned short*)((char*)d_ws + 256);   // bf16 [8192][512]

    hipLaunchKernelGGL(normalize_kernel, dim3(NROWS / 4), dim3(256), 0, stream,
                       emb_i, emb_j, rep, ws);
    hipLaunchKernelGGL(gram_kernel, dim3(GRID_G), dim3(512), 0, stream, rep, ws, out);
}